// Round 13
// baseline (363.307 us; speedup 1.0000x reference)
//
#include <hip/hip_runtime.h>
#include <hip/hip_bf16.h>

// CxNNxNN attention. B=8, C=64, H=W=256, head=8, N=8.
// token n = (h&7)*8 + (w&7)  [64], feature d = (h>>3)*32 + (w>>3)  [1024].

typedef __attribute__((ext_vector_type(8))) short short8;  // 8 bf16 (4 VGPR)
typedef __attribute__((ext_vector_type(4))) float f4;      // MFMA acc
typedef unsigned short u16;

#define PST 72  // bf16 plane row stride (ushorts)

// ---------------- bf16 hi/lo helpers ----------------
__device__ __forceinline__ float tof(u16 u) {
  return __builtin_bit_cast(float, ((unsigned)u) << 16);
}
__device__ __forceinline__ void fsplit(float o, u16& h, u16& l) {
  unsigned u = __builtin_bit_cast(unsigned, o);
  h = (u16)(u >> 16);  // truncate; lo compensates
  float hf = __builtin_bit_cast(float, u & 0xffff0000u);
  l = (u16)(__builtin_bit_cast(unsigned, o - hf) >> 16);
}
__device__ __forceinline__ short8 ldfrag(const u16* p, int row, int ko) {
  return *(const short8*)&p[row * PST + ko];
}

// ---------------- K1/K3: pointwise GEMM on MFMA (validated R12) ----------------
template <int OC>
__global__ __launch_bounds__(256) void k_pwm(const float* in,
                                             const float* __restrict__ w,
                                             float* outp) {
  constexpr int MT = OC / 64;
  __shared__ u16 XTh[64 * PST], XTl[64 * PST];
  const int t = threadIdx.x;
  const int px = t & 63, cg = t >> 6;
  const int g = (t >> 4) & 3, r16 = t & 15;
  const int oc0 = cg * 16 * MT;
  const size_t pix0 = (size_t)blockIdx.x * 256;  // 4 tiles of 64 px
  const int b = (int)(pix0 >> 16);
  const int hwb = (int)(pix0 & 65535);
  const float* ibase = in + ((size_t)b << 22);

  short8 ah[MT][2], al[MT][2];
#pragma unroll
  for (int m = 0; m < MT; ++m)
#pragma unroll
    for (int ks = 0; ks < 2; ++ks) {
      const float* wr = w + (oc0 + m * 16 + r16) * 64 + ks * 32 + g * 8;
      float4 a0 = *(const float4*)wr;
      float4 a1 = *(const float4*)(wr + 4);
      float av[8] = {a0.x, a0.y, a0.z, a0.w, a1.x, a1.y, a1.z, a1.w};
      short8 h8, l8;
#pragma unroll
      for (int e = 0; e < 8; ++e) {
        u16 h, l;
        fsplit(av[e], h, l);
        h8[e] = (short)h;
        l8[e] = (short)l;
      }
      ah[m][ks] = h8;
      al[m][ks] = l8;
    }

  float xr[16];
#pragma unroll
  for (int j = 0; j < 16; ++j)
    xr[j] = ibase[((size_t)(cg * 16 + j) << 16) + hwb + px];

#pragma unroll 1
  for (int tau = 0; tau < 4; ++tau) {
    const int hw0 = hwb + tau * 64;
#pragma unroll
    for (int jh = 0; jh < 2; ++jh) {
      short8 hv, lv;
#pragma unroll
      for (int e = 0; e < 8; ++e) {
        u16 h, l;
        fsplit(xr[jh * 8 + e], h, l);
        hv[e] = (short)h;
        lv[e] = (short)l;
      }
      *(short8*)&XTh[px * PST + cg * 16 + jh * 8] = hv;
      *(short8*)&XTl[px * PST + cg * 16 + jh * 8] = lv;
    }
    __syncthreads();
    if (tau < 3) {
#pragma unroll
      for (int j = 0; j < 16; ++j)
        xr[j] = ibase[((size_t)(cg * 16 + j) << 16) + hw0 + 64 + px];
    }
    float* ob = outp + (((size_t)b * OC) << 16) + hw0;
#pragma unroll
    for (int m = 0; m < MT; ++m)
#pragma unroll
      for (int nt = 0; nt < 4; ++nt) {
        f4 acc;
#pragma unroll
        for (int e = 0; e < 4; ++e) acc[e] = 0.f;
#pragma unroll
        for (int ks = 0; ks < 2; ++ks) {
          short8 bh = ldfrag(XTh, nt * 16 + r16, ks * 32 + g * 8);
          short8 bl = ldfrag(XTl, nt * 16 + r16, ks * 32 + g * 8);
          acc = __builtin_amdgcn_mfma_f32_16x16x32_bf16(ah[m][ks], bh, acc, 0, 0, 0);
          acc = __builtin_amdgcn_mfma_f32_16x16x32_bf16(ah[m][ks], bl, acc, 0, 0, 0);
          acc = __builtin_amdgcn_mfma_f32_16x16x32_bf16(al[m][ks], bh, acc, 0, 0, 0);
        }
#pragma unroll
        for (int e = 0; e < 4; ++e) {
          int oc = oc0 + m * 16 + g * 4 + e;
          ob[((size_t)oc << 16) + nt * 16 + r16] = acc[e];
        }
      }
    __syncthreads();
  }
}

// ---------------- batched branchless depthwise-3x3 conv ----------------
// R12 profile: k_qkt 136us = 40k cyc/chunk vs ~5k of work. Old conv_run
// interleaved guarded loads with uses -> up to 24 SERIALIZED ~900cyc load
// latencies per chunk. Fix: conv_load issues all 24 loads per plane
// branchlessly (clamped addresses) into flat regs -> ONE latency window;
// conv_eval masks invalid rows via weights (w*0*garbage = 0, exact).
struct ConvData {
  float4 f[2][6];   // [rr][2*dy+half]
  float hl[2][6];   // [rr][2*dy + (0=left,1=right)]
  float m[2][3];    // row-valid masks
};

__device__ __forceinline__ void conv_load(const float* __restrict__ pl, int cd,
                                          int t, ConvData& c) {
#pragma unroll
  for (int rr = 0; rr < 2; ++rr) {
    int r = t + rr * 256;
    int lr = r >> 5, w0 = r & 31;
    int h = cd * 16 + lr;
#pragma unroll
    for (int dy = 0; dy < 3; ++dy) {
      int hy = h + dy - 1;
      c.m[rr][dy] = (hy >= 0 && hy < 256) ? 1.f : 0.f;
      int hyc = hy < 0 ? 0 : (hy > 255 ? 255 : hy);
      const float* rp = pl + hyc * 256;
      c.f[rr][2 * dy] = *(const float4*)(rp + w0 * 8);
      c.f[rr][2 * dy + 1] = *(const float4*)(rp + w0 * 8 + 4);
      c.hl[rr][2 * dy] = rp[w0 ? w0 * 8 - 1 : 0];
      c.hl[rr][2 * dy + 1] = rp[w0 < 31 ? w0 * 8 + 8 : 255];
    }
  }
}

__device__ __forceinline__ void conv_eval8(const float* __restrict__ w9,
                                           const ConvData& c, int rr, int w0,
                                           float o[8]) {
  float wm[9];
#pragma unroll
  for (int dy = 0; dy < 3; ++dy) {
    float mm = c.m[rr][dy];
    wm[3 * dy] = w9[3 * dy] * mm;
    wm[3 * dy + 1] = w9[3 * dy + 1] * mm;
    wm[3 * dy + 2] = w9[3 * dy + 2] * mm;
  }
  float rv[3][10];
#pragma unroll
  for (int dy = 0; dy < 3; ++dy) {
    float4 a = c.f[rr][2 * dy], b4 = c.f[rr][2 * dy + 1];
    rv[dy][0] = w0 ? c.hl[rr][2 * dy] : 0.f;
    rv[dy][1] = a.x;  rv[dy][2] = a.y;  rv[dy][3] = a.z;  rv[dy][4] = a.w;
    rv[dy][5] = b4.x; rv[dy][6] = b4.y; rv[dy][7] = b4.z; rv[dy][8] = b4.w;
    rv[dy][9] = (w0 < 31) ? c.hl[rr][2 * dy + 1] : 0.f;
  }
#pragma unroll
  for (int i = 0; i < 8; ++i) {
    o[i] = fmaf(wm[0], rv[0][i], fmaf(wm[1], rv[0][i + 1], fmaf(wm[2], rv[0][i + 2],
            fmaf(wm[3], rv[1][i], fmaf(wm[4], rv[1][i + 1], fmaf(wm[5], rv[1][i + 2],
            fmaf(wm[6], rv[2][i], fmaf(wm[7], rv[2][i + 1], wm[8] * rv[2][i + 2]))))))));
  }
}

// stage Q/K chunk as hi/lo planes [64 n][PST d]
__device__ __forceinline__ void stage_nk(const float* __restrict__ pl,
                                         const float* __restrict__ w9,
                                         u16* __restrict__ ph,
                                         u16* __restrict__ plo, int cd, int t) {
  ConvData c;
  conv_load(pl, cd, t, c);  // all 24 loads in one window
  const int w0 = t & 31;
#pragma unroll
  for (int rr = 0; rr < 2; ++rr) {
    int lr = (t >> 5) + rr * 8;
    int nb = (lr & 7) * 8;
    int dcol = ((lr >> 3) << 5) + w0;
    float o[8];
    conv_eval8(w9, c, rr, w0, o);
#pragma unroll
    for (int i = 0; i < 8; ++i) {
      u16 h, l;
      fsplit(o[i], h, l);
      ph[(nb + i) * PST + dcol] = h;
      plo[(nb + i) * PST + dcol] = l;
    }
  }
}

// stage V chunk TRANSPOSED [64 d][PST n]: packed b128 writes
__device__ __forceinline__ void stage_vt(const float* __restrict__ pl,
                                         const float* __restrict__ w9,
                                         u16* __restrict__ ph,
                                         u16* __restrict__ plo, int cd, int t) {
  ConvData c;
  conv_load(pl, cd, t, c);
  const int w0 = t & 31;
#pragma unroll
  for (int rr = 0; rr < 2; ++rr) {
    int lr = (t >> 5) + rr * 8;
    int nb = (lr & 7) * 8;
    int dcol = ((lr >> 3) << 5) + w0;
    float o[8];
    conv_eval8(w9, c, rr, w0, o);
    short8 hv, lv;
#pragma unroll
    for (int i = 0; i < 8; ++i) {
      u16 h, l;
      fsplit(o[i], h, l);
      hv[i] = (short)h;
      lv[i] = (short)l;
    }
    *(short8*)&ph[dcol * PST + nb] = hv;
    *(short8*)&plo[dcol * PST + nb] = lv;
  }
}

// ---------------- K2a: QK^T partial over a d-half ----------------
__global__ __launch_bounds__(256) void k_qkt(float* qkv0,
                                             const float* __restrict__ wdw) {
  __shared__ u16 SAh[64 * PST], SAl[64 * PST];
  __shared__ u16 SBh[64 * PST], SBl[64 * PST];
  __shared__ float red[64 * 8];
  const int t = threadIdx.x;
  const int u = blockIdx.x >> 1, hd = blockIdx.x & 1;
  const int b = u >> 6, ch = u & 63;
  float* qpl = qkv0 + (((size_t)b * 192 + ch) << 16);
  const float* kpl = qkv0 + (((size_t)b * 192 + 64 + ch) << 16);
  float wq[9], wk[9];
#pragma unroll
  for (int i = 0; i < 9; ++i) {
    wq[i] = wdw[ch * 9 + i];
    wk[i] = wdw[(64 + ch) * 9 + i];
  }
  const int wid = t >> 6, g = (t >> 4) & 3, r16 = t & 15;
  f4 acc[4];
#pragma unroll
  for (int cb = 0; cb < 4; ++cb)
#pragma unroll
    for (int e = 0; e < 4; ++e) acc[cb][e] = 0.f;
  float sqQ = 0.f, sqK = 0.f;

  for (int c8 = 0; c8 < 8; ++c8) {
    const int cd = hd * 8 + c8;
    stage_nk(qpl, wq, SAh, SAl, cd, t);
    stage_nk(kpl, wk, SBh, SBl, cd, t);
    __syncthreads();
    {  // sumsq partials (hi+lo reconstructed): row n=t>>2, 16 cols
      const int n = t >> 2, c0 = (t & 3) << 4;
#pragma unroll
      for (int h2 = 0; h2 < 2; ++h2) {
        short8 qh = *(const short8*)&SAh[n * PST + c0 + 8 * h2];
        short8 ql = *(const short8*)&SAl[n * PST + c0 + 8 * h2];
        short8 kh = *(const short8*)&SBh[n * PST + c0 + 8 * h2];
        short8 kl = *(const short8*)&SBl[n * PST + c0 + 8 * h2];
#pragma unroll
        for (int e = 0; e < 8; ++e) {
          float qv = tof((u16)qh[e]) + tof((u16)ql[e]);
          float kv = tof((u16)kh[e]) + tof((u16)kl[e]);
          sqQ = fmaf(qv, qv, sqQ);
          sqK = fmaf(kv, kv, sqK);
        }
      }
    }
#pragma unroll
    for (int ks = 0; ks < 2; ++ks) {
      const int ko = ks * 32 + g * 8;
      short8 ah = ldfrag(SAh, wid * 16 + r16, ko);
      short8 al = ldfrag(SAl, wid * 16 + r16, ko);
#pragma unroll
      for (int cb = 0; cb < 4; ++cb) {
        short8 bh = ldfrag(SBh, cb * 16 + r16, ko);
        short8 bl = ldfrag(SBl, cb * 16 + r16, ko);
        acc[cb] = __builtin_amdgcn_mfma_f32_16x16x32_bf16(ah, bh, acc[cb], 0, 0, 0);
        acc[cb] = __builtin_amdgcn_mfma_f32_16x16x32_bf16(ah, bl, acc[cb], 0, 0, 0);
        acc[cb] = __builtin_amdgcn_mfma_f32_16x16x32_bf16(al, bh, acc[cb], 0, 0, 0);
      }
    }
    __syncthreads();
  }

  red[(t >> 2) * 8 + (t & 3)] = sqQ;
  red[(t >> 2) * 8 + 4 + (t & 3)] = sqK;
  __syncthreads();
  float* stash = qpl + hd * 32768 + 256;  // S[4096] then sumsq[128]
  if (t < 128) {
    int n = t & 63;
    int o = (t >> 6) * 4;
    float s = red[n * 8 + o] + red[n * 8 + o + 1] + red[n * 8 + o + 2] +
              red[n * 8 + o + 3];
    stash[4096 + (t >> 6) * 64 + n] = s;  // 0..63 = Q, 64..127 = K
  }
#pragma unroll
  for (int cb = 0; cb < 4; ++cb)
#pragma unroll
    for (int r = 0; r < 4; ++r) {
      int n = wid * 16 + g * 4 + r, m = cb * 16 + r16;
      stash[n * 64 + m] = acc[cb][r];
    }
}

// ---------------- K2b: softmax + PV over a d-half ----------------
__global__ __launch_bounds__(256) void k_pv(const float* qkv0,
                                            const float* __restrict__ wdw,
                                            const float* __restrict__ temperature,
                                            float* __restrict__ out) {
  __shared__ u16 Ph[64 * PST], Pl[64 * PST];
  __shared__ u16 Vh[64 * PST], Vl[64 * PST];
  __shared__ float invk[64];
  const int t = threadIdx.x;
  const int u = blockIdx.x >> 1, hd = blockIdx.x & 1;
  const int b = u >> 6, ch = u & 63;
  const float* vpl = qkv0 + (((size_t)b * 192 + 128 + ch) << 16);
  const float* sb0 = qkv0 + (((size_t)b * 192 + ch) << 16) + 256;
  const float* sb1 = sb0 + 32768;
  float wv[9];
#pragma unroll
  for (int i = 0; i < 9; ++i) wv[i] = wdw[(128 + ch) * 9 + i];
  const float tscale = temperature[ch >> 3];
  const int wid = t >> 6, g = (t >> 4) & 3, r16 = t & 15;

  if (t < 64) {
    float s = sb0[4096 + 64 + t] + sb1[4096 + 64 + t];
    invk[t] = 1.f / fmaxf(sqrtf(s), 1e-12f);
  }
  __syncthreads();

  const int row = wid * 16 + r16;
  float sq = sb0[4096 + row] + sb1[4096 + row];
  const float invq = 1.f / fmaxf(sqrtf(sq), 1e-12f);
  float sv[16];
  const float* s0r = sb0 + row * 64 + g * 16;
  const float* s1r = sb1 + row * 64 + g * 16;
  float mx = -1e30f;
#pragma unroll
  for (int j = 0; j < 16; ++j) {
    sv[j] = (s0r[j] + s1r[j]) * invq * invk[g * 16 + j] * tscale;
    mx = fmaxf(mx, sv[j]);
  }
  mx = fmaxf(mx, __shfl_xor(mx, 16));
  mx = fmaxf(mx, __shfl_xor(mx, 32));
  float ss = 0.f;
#pragma unroll
  for (int j = 0; j < 16; ++j) {
    sv[j] = __expf(sv[j] - mx);
    ss += sv[j];
  }
  ss += __shfl_xor(ss, 16);
  ss += __shfl_xor(ss, 32);
  const float rs = 1.f / ss;
  short8 h0, h1, l0, l1;
#pragma unroll
  for (int j = 0; j < 8; ++j) {
    u16 h, l;
    fsplit(sv[j] * rs, h, l);
    h0[j] = (short)h; l0[j] = (short)l;
    fsplit(sv[8 + j] * rs, h, l);
    h1[j] = (short)h; l1[j] = (short)l;
  }
  *(short8*)&Ph[row * PST + g * 16] = h0;
  *(short8*)&Ph[row * PST + g * 16 + 8] = h1;
  *(short8*)&Pl[row * PST + g * 16] = l0;
  *(short8*)&Pl[row * PST + g * 16 + 8] = l1;
  __syncthreads();

  short8 pah[2], pal[2];
#pragma unroll
  for (int ks = 0; ks < 2; ++ks) {
    pah[ks] = ldfrag(Ph, wid * 16 + r16, ks * 32 + g * 8);
    pal[ks] = ldfrag(Pl, wid * 16 + r16, ks * 32 + g * 8);
  }

  size_t obase = ((size_t)b * 64 + ch) << 16;
  for (int c8 = 0; c8 < 8; ++c8) {
    const int cd = hd * 8 + c8;
    stage_vt(vpl, wv, Vh, Vl, cd, t);
    __syncthreads();
    f4 po[4];
#pragma unroll
    for (int cb = 0; cb < 4; ++cb)
#pragma unroll
      for (int e = 0; e < 4; ++e) po[cb][e] = 0.f;
#pragma unroll
    for (int ks = 0; ks < 2; ++ks) {
      const int ko = ks * 32 + g * 8;
#pragma unroll
      for (int cb = 0; cb < 4; ++cb) {
        short8 bh = ldfrag(Vh, cb * 16 + r16, ko);
        short8 bl = ldfrag(Vl, cb * 16 + r16, ko);
        po[cb] = __builtin_amdgcn_mfma_f32_16x16x32_bf16(pah[ks], bh, po[cb], 0, 0, 0);
        po[cb] = __builtin_amdgcn_mfma_f32_16x16x32_bf16(pah[ks], bl, po[cb], 0, 0, 0);
        po[cb] = __builtin_amdgcn_mfma_f32_16x16x32_bf16(pal[ks], bh, po[cb], 0, 0, 0);
      }
    }
#pragma unroll
    for (int cb = 0; cb < 4; ++cb)
#pragma unroll
      for (int r = 0; r < 4; ++r) {
        int n = wid * 16 + g * 4 + r;
        int d = cd * 64 + cb * 16 + r16;
        int hh = ((d >> 5) << 3) + (n >> 3);
        int ww = ((d & 31) << 3) + (n & 7);
        out[obase + hh * 256 + ww] = po[cb][r];
      }
    __syncthreads();
  }
}

extern "C" void kernel_launch(void* const* d_in, const int* in_sizes, int n_in,
                              void* d_out, int out_size, void* d_ws,
                              size_t ws_size, hipStream_t stream) {
  const float* x = (const float*)d_in[0];
  const float* wqkv = (const float*)d_in[1];
  const float* wdw = (const float*)d_in[2];
  const float* wproj = (const float*)d_in[3];
  const float* temp = (const float*)d_in[4];
  float* out = (float*)d_out;
  float* qkv0 = (float*)d_ws;  // 402,653,184 bytes (S/sumsq stash inside)

  k_pwm<192><<<2048, 256, 0, stream>>>(x, wqkv, qkv0);
  k_qkt<<<1024, 256, 0, stream>>>(qkv0, wdw);
  k_pv<<<1024, 256, 0, stream>>>(qkv0, wdw, temp, out);
  k_pwm<64><<<2048, 256, 0, stream>>>(out, wproj, out);
}

// Round 14
// 313.564 us; speedup vs baseline: 1.1586x; 1.1586x over previous
//
#include <hip/hip_runtime.h>
#include <hip/hip_bf16.h>

// CxNNxNN attention. B=8, C=64, H=W=256, head=8, N=8.
// token n = (h&7)*8 + (w&7)  [64], feature d = (h>>3)*32 + (w>>3)  [1024].

typedef __attribute__((ext_vector_type(8))) short short8;  // 8 bf16 (4 VGPR)
typedef __attribute__((ext_vector_type(4))) float f4;      // MFMA acc
typedef unsigned short u16;

#define PST 72  // bf16 plane row stride (ushorts)

// ---------------- bf16 hi/lo helpers ----------------
__device__ __forceinline__ float tof(u16 u) {
  return __builtin_bit_cast(float, ((unsigned)u) << 16);
}
__device__ __forceinline__ void fsplit(float o, u16& h, u16& l) {
  unsigned u = __builtin_bit_cast(unsigned, o);
  h = (u16)(u >> 16);  // truncate; lo compensates
  float hf = __builtin_bit_cast(float, u & 0xffff0000u);
  l = (u16)(__builtin_bit_cast(unsigned, o - hf) >> 16);
}
__device__ __forceinline__ short8 ldfrag(const u16* p, int row, int ko) {
  return *(const short8*)&p[row * PST + ko];
}

// async global->LDS row DMA: one instr = one 256-float row (64 lanes x 16B)
__device__ __forceinline__ void gload_row(const float* g, float* l) {
  __builtin_amdgcn_global_load_lds(
      (const __attribute__((address_space(1))) unsigned*)g,
      (__attribute__((address_space(3))) unsigned*)l, 16, 0, 0);
}

// ---------------- K1/K3: pointwise GEMM on MFMA (validated R12) ----------------
template <int OC>
__global__ __launch_bounds__(256) void k_pwm(const float* in,
                                             const float* __restrict__ w,
                                             float* outp) {
  constexpr int MT = OC / 64;
  __shared__ u16 XTh[64 * PST], XTl[64 * PST];
  const int t = threadIdx.x;
  const int px = t & 63, cg = t >> 6;
  const int g = (t >> 4) & 3, r16 = t & 15;
  const int oc0 = cg * 16 * MT;
  const size_t pix0 = (size_t)blockIdx.x * 256;  // 4 tiles of 64 px
  const int b = (int)(pix0 >> 16);
  const int hwb = (int)(pix0 & 65535);
  const float* ibase = in + ((size_t)b << 22);

  short8 ah[MT][2], al[MT][2];
#pragma unroll
  for (int m = 0; m < MT; ++m)
#pragma unroll
    for (int ks = 0; ks < 2; ++ks) {
      const float* wr = w + (oc0 + m * 16 + r16) * 64 + ks * 32 + g * 8;
      float4 a0 = *(const float4*)wr;
      float4 a1 = *(const float4*)(wr + 4);
      float av[8] = {a0.x, a0.y, a0.z, a0.w, a1.x, a1.y, a1.z, a1.w};
      short8 h8, l8;
#pragma unroll
      for (int e = 0; e < 8; ++e) {
        u16 h, l;
        fsplit(av[e], h, l);
        h8[e] = (short)h;
        l8[e] = (short)l;
      }
      ah[m][ks] = h8;
      al[m][ks] = l8;
    }

  float xr[16];
#pragma unroll
  for (int j = 0; j < 16; ++j)
    xr[j] = ibase[((size_t)(cg * 16 + j) << 16) + hwb + px];

#pragma unroll 1
  for (int tau = 0; tau < 4; ++tau) {
    const int hw0 = hwb + tau * 64;
#pragma unroll
    for (int jh = 0; jh < 2; ++jh) {
      short8 hv, lv;
#pragma unroll
      for (int e = 0; e < 8; ++e) {
        u16 h, l;
        fsplit(xr[jh * 8 + e], h, l);
        hv[e] = (short)h;
        lv[e] = (short)l;
      }
      *(short8*)&XTh[px * PST + cg * 16 + jh * 8] = hv;
      *(short8*)&XTl[px * PST + cg * 16 + jh * 8] = lv;
    }
    __syncthreads();
    if (tau < 3) {
#pragma unroll
      for (int j = 0; j < 16; ++j)
        xr[j] = ibase[((size_t)(cg * 16 + j) << 16) + hw0 + 64 + px];
    }
    float* ob = outp + (((size_t)b * OC) << 16) + hw0;
#pragma unroll
    for (int m = 0; m < MT; ++m)
#pragma unroll
      for (int nt = 0; nt < 4; ++nt) {
        f4 acc;
#pragma unroll
        for (int e = 0; e < 4; ++e) acc[e] = 0.f;
#pragma unroll
        for (int ks = 0; ks < 2; ++ks) {
          short8 bh = ldfrag(XTh, nt * 16 + r16, ks * 32 + g * 8);
          short8 bl = ldfrag(XTl, nt * 16 + r16, ks * 32 + g * 8);
          acc = __builtin_amdgcn_mfma_f32_16x16x32_bf16(ah[m][ks], bh, acc, 0, 0, 0);
          acc = __builtin_amdgcn_mfma_f32_16x16x32_bf16(ah[m][ks], bl, acc, 0, 0, 0);
          acc = __builtin_amdgcn_mfma_f32_16x16x32_bf16(al[m][ks], bh, acc, 0, 0, 0);
        }
#pragma unroll
        for (int e = 0; e < 4; ++e) {
          int oc = oc0 + m * 16 + g * 4 + e;
          ob[((size_t)oc << 16) + nt * 16 + r16] = acc[e];
        }
      }
    __syncthreads();
  }
}

// ---- conv eval from LDS-staged raw rows (raw row j = image row cd*16-1+j) ----
// R13 post-mortem: register-batched global loads failed (allocator re-split
// the 60-float ConvData). R14: raw rows DMA'd into LDS via global_load_lds
// (async, zero VGPR), conv reads LDS (120cyc, throughput-bound). Vertical
// pad via weight masks (w*0*garbage=0 exact), horizontal pad via selects.
__device__ __forceinline__ void conv_eval_lds(const float* __restrict__ raw,
                                              const float* __restrict__ w9,
                                              int lr, int w0, int cd,
                                              float o[8]) {
  float wm[9], rv[3][10];
#pragma unroll
  for (int dy = 0; dy < 3; ++dy) {
    int hy = cd * 16 + lr - 1 + dy;
    float mm = (hy >= 0 && hy < 256) ? 1.f : 0.f;
    wm[3 * dy] = w9[3 * dy] * mm;
    wm[3 * dy + 1] = w9[3 * dy + 1] * mm;
    wm[3 * dy + 2] = w9[3 * dy + 2] * mm;
    const float* rp = raw + (lr + dy) * 256;
    float4 l0 = *(const float4*)(rp + w0 * 8);
    float4 l1 = *(const float4*)(rp + w0 * 8 + 4);
    float sL = rp[w0 ? w0 * 8 - 1 : 0];
    float sR = rp[w0 * 8 + 8];  // w0=31: in-LDS garbage, selected away
    rv[dy][0] = w0 ? sL : 0.f;
    rv[dy][1] = l0.x; rv[dy][2] = l0.y; rv[dy][3] = l0.z; rv[dy][4] = l0.w;
    rv[dy][5] = l1.x; rv[dy][6] = l1.y; rv[dy][7] = l1.z; rv[dy][8] = l1.w;
    rv[dy][9] = (w0 < 31) ? sR : 0.f;
  }
#pragma unroll
  for (int i = 0; i < 8; ++i) {
    o[i] = fmaf(wm[0], rv[0][i], fmaf(wm[1], rv[0][i + 1], fmaf(wm[2], rv[0][i + 2],
            fmaf(wm[3], rv[1][i], fmaf(wm[4], rv[1][i + 1], fmaf(wm[5], rv[1][i + 2],
            fmaf(wm[6], rv[2][i], fmaf(wm[7], rv[2][i + 1], wm[8] * rv[2][i + 2]))))))));
  }
}

// issue 18 row-DMAs for Q and K (wave w: Q0-8 / Q9-17 / K0-8 / K9-17)
__device__ __forceinline__ void issue_raw_qk(const float* qpl, const float* kpl,
                                             float* rawQ, float* rawK, int cd,
                                             int wid, int lane) {
  const float* src = (wid & 2) ? kpl : qpl;
  float* dst = (wid & 2) ? rawK : rawQ;
#pragma unroll
  for (int j = 0; j < 9; ++j) {
    int rr = (wid & 1) * 9 + j;
    int hy = cd * 16 - 1 + rr;
    hy = hy < 0 ? 0 : (hy > 255 ? 255 : hy);
    gload_row(src + hy * 256 + lane * 4, dst + rr * 256);
  }
}

// issue 18 row-DMAs for V (wave w: rows w*5..min(+5,18))
__device__ __forceinline__ void issue_raw_v(const float* vpl, float* rawV,
                                            int cd, int wid, int lane) {
#pragma unroll
  for (int j = 0; j < 5; ++j) {
    int rr = wid * 5 + j;
    if (rr < 18) {
      int hy = cd * 16 - 1 + rr;
      hy = hy < 0 ? 0 : (hy > 255 ? 255 : hy);
      gload_row(vpl + hy * 256 + lane * 4, rawV + rr * 256);
    }
  }
}

// ---------------- K2a: QK^T partial over a d-half ----------------
// Pipeline per chunk: [raw tau in flight] waitcnt+barrier -> conv eval from
// raw -> write planes -> barrier (raw consumed) -> ISSUE raw tau+1 (async,
// flies under next phase) -> sumsq + MFMA on planes -> loop.
__global__ __launch_bounds__(256) void k_qkt(float* qkv0,
                                             const float* __restrict__ wdw) {
  __shared__ float rawQ[18 * 256];
  __shared__ float rawK[18 * 256];
  __shared__ u16 SAh[64 * PST], SAl[64 * PST];
  __shared__ u16 SBh[64 * PST], SBl[64 * PST];
  __shared__ float red[64 * 8];
  const int t = threadIdx.x;
  const int u = blockIdx.x >> 1, hd = blockIdx.x & 1;
  const int b = u >> 6, ch = u & 63;
  float* qpl = qkv0 + (((size_t)b * 192 + ch) << 16);
  const float* kpl = qkv0 + (((size_t)b * 192 + 64 + ch) << 16);
  const int wid = t >> 6, lane = t & 63;
  const int g = (t >> 4) & 3, r16 = t & 15;
  const int lr0 = t >> 5, w0 = t & 31;

  issue_raw_qk(qpl, kpl, rawQ, rawK, hd * 8, wid, lane);  // chunk 0, async

  float wq[9], wk[9];
#pragma unroll
  for (int i = 0; i < 9; ++i) {  // overlap with DMA
    wq[i] = wdw[ch * 9 + i];
    wk[i] = wdw[(64 + ch) * 9 + i];
  }
  f4 acc[4];
#pragma unroll
  for (int cb = 0; cb < 4; ++cb)
#pragma unroll
    for (int e = 0; e < 4; ++e) acc[cb][e] = 0.f;
  float sqQ = 0.f, sqK = 0.f;

#pragma unroll 1
  for (int c8 = 0; c8 < 8; ++c8) {
    const int cd = hd * 8 + c8;
    asm volatile("s_waitcnt vmcnt(0)" ::: "memory");
    __syncthreads();  // raw tau ready (all waves)
    // eval Q and K runs (lr0, w0) and (lr0+8, w0); write bf16 hi/lo planes
#pragma unroll
    for (int rr = 0; rr < 2; ++rr) {
      int lr = lr0 + rr * 8;
      int nb = (lr & 7) * 8;
      int dcol = ((lr >> 3) << 5) + w0;
      float oq[8], ok[8];
      conv_eval_lds(rawQ, wq, lr, w0, cd, oq);
      conv_eval_lds(rawK, wk, lr, w0, cd, ok);
#pragma unroll
      for (int i = 0; i < 8; ++i) {
        u16 h, l;
        fsplit(oq[i], h, l);
        SAh[(nb + i) * PST + dcol] = h;
        SAl[(nb + i) * PST + dcol] = l;
        fsplit(ok[i], h, l);
        SBh[(nb + i) * PST + dcol] = h;
        SBl[(nb + i) * PST + dcol] = l;
      }
    }
    __syncthreads();  // planes ready; raw consumed
    if (c8 < 7)       // async DMA for tau+1 flies under sumsq+MFMA
      issue_raw_qk(qpl, kpl, rawQ, rawK, cd + 1, wid, lane);
    {  // sumsq partials (hi+lo reconstructed): row n=t>>2, 16 cols
      const int n = t >> 2, c0 = (t & 3) << 4;
#pragma unroll
      for (int h2 = 0; h2 < 2; ++h2) {
        short8 qh = *(const short8*)&SAh[n * PST + c0 + 8 * h2];
        short8 ql = *(const short8*)&SAl[n * PST + c0 + 8 * h2];
        short8 kh = *(const short8*)&SBh[n * PST + c0 + 8 * h2];
        short8 kl = *(const short8*)&SBl[n * PST + c0 + 8 * h2];
#pragma unroll
        for (int e = 0; e < 8; ++e) {
          float qv = tof((u16)qh[e]) + tof((u16)ql[e]);
          float kv = tof((u16)kh[e]) + tof((u16)kl[e]);
          sqQ = fmaf(qv, qv, sqQ);
          sqK = fmaf(kv, kv, sqK);
        }
      }
    }
#pragma unroll
    for (int ks = 0; ks < 2; ++ks) {
      const int ko = ks * 32 + g * 8;
      short8 ah = ldfrag(SAh, wid * 16 + r16, ko);
      short8 al = ldfrag(SAl, wid * 16 + r16, ko);
#pragma unroll
      for (int cb = 0; cb < 4; ++cb) {
        short8 bh = ldfrag(SBh, cb * 16 + r16, ko);
        short8 bl = ldfrag(SBl, cb * 16 + r16, ko);
        acc[cb] = __builtin_amdgcn_mfma_f32_16x16x32_bf16(ah, bh, acc[cb], 0, 0, 0);
        acc[cb] = __builtin_amdgcn_mfma_f32_16x16x32_bf16(ah, bl, acc[cb], 0, 0, 0);
        acc[cb] = __builtin_amdgcn_mfma_f32_16x16x32_bf16(al, bh, acc[cb], 0, 0, 0);
      }
    }
  }

  __syncthreads();
  red[(t >> 2) * 8 + (t & 3)] = sqQ;
  red[(t >> 2) * 8 + 4 + (t & 3)] = sqK;
  __syncthreads();
  float* stash = qpl + hd * 32768 + 256;  // S[4096] then sumsq[128]
  if (t < 128) {
    int n = t & 63;
    int o = (t >> 6) * 4;
    float s = red[n * 8 + o] + red[n * 8 + o + 1] + red[n * 8 + o + 2] +
              red[n * 8 + o + 3];
    stash[4096 + (t >> 6) * 64 + n] = s;  // 0..63 = Q, 64..127 = K
  }
#pragma unroll
  for (int cb = 0; cb < 4; ++cb)
#pragma unroll
    for (int r = 0; r < 4; ++r) {
      int n = wid * 16 + g * 4 + r, m = cb * 16 + r16;
      stash[n * 64 + m] = acc[cb][r];
    }
}

// ---------------- K2b: softmax + PV over a d-half ----------------
__global__ __launch_bounds__(256) void k_pv(const float* qkv0,
                                            const float* __restrict__ wdw,
                                            const float* __restrict__ temperature,
                                            float* __restrict__ out) {
  __shared__ float rawV[18 * 256];
  __shared__ u16 Ph[64 * PST], Pl[64 * PST];
  __shared__ u16 Vh[64 * PST], Vl[64 * PST];
  __shared__ float invk[64];
  const int t = threadIdx.x;
  const int u = blockIdx.x >> 1, hd = blockIdx.x & 1;
  const int b = u >> 6, ch = u & 63;
  const float* vpl = qkv0 + (((size_t)b * 192 + 128 + ch) << 16);
  const float* sb0 = qkv0 + (((size_t)b * 192 + ch) << 16) + 256;
  const float* sb1 = sb0 + 32768;
  const int wid = t >> 6, lane = t & 63;
  const int g = (t >> 4) & 3, r16 = t & 15;
  const int lr0 = t >> 5, w0 = t & 31;

  issue_raw_v(vpl, rawV, hd * 8, wid, lane);  // chunk 0, flies under softmax

  float wv[9];
#pragma unroll
  for (int i = 0; i < 9; ++i) wv[i] = wdw[(128 + ch) * 9 + i];
  const float tscale = temperature[ch >> 3];

  if (t < 64) {
    float s = sb0[4096 + 64 + t] + sb1[4096 + 64 + t];
    invk[t] = 1.f / fmaxf(sqrtf(s), 1e-12f);
  }
  __syncthreads();

  const int row = wid * 16 + r16;
  float sq = sb0[4096 + row] + sb1[4096 + row];
  const float invq = 1.f / fmaxf(sqrtf(sq), 1e-12f);
  float sv[16];
  const float* s0r = sb0 + row * 64 + g * 16;
  const float* s1r = sb1 + row * 64 + g * 16;
  float mx = -1e30f;
#pragma unroll
  for (int j = 0; j < 16; ++j) {
    sv[j] = (s0r[j] + s1r[j]) * invq * invk[g * 16 + j] * tscale;
    mx = fmaxf(mx, sv[j]);
  }
  mx = fmaxf(mx, __shfl_xor(mx, 16));
  mx = fmaxf(mx, __shfl_xor(mx, 32));
  float ss = 0.f;
#pragma unroll
  for (int j = 0; j < 16; ++j) {
    sv[j] = __expf(sv[j] - mx);
    ss += sv[j];
  }
  ss += __shfl_xor(ss, 16);
  ss += __shfl_xor(ss, 32);
  const float rs = 1.f / ss;
  short8 h0, h1, l0, l1;
#pragma unroll
  for (int j = 0; j < 8; ++j) {
    u16 h, l;
    fsplit(sv[j] * rs, h, l);
    h0[j] = (short)h; l0[j] = (short)l;
    fsplit(sv[8 + j] * rs, h, l);
    h1[j] = (short)h; l1[j] = (short)l;
  }
  *(short8*)&Ph[row * PST + g * 16] = h0;
  *(short8*)&Ph[row * PST + g * 16 + 8] = h1;
  *(short8*)&Pl[row * PST + g * 16] = l0;
  *(short8*)&Pl[row * PST + g * 16 + 8] = l1;
  __syncthreads();

  short8 pah[2], pal[2];
#pragma unroll
  for (int ks = 0; ks < 2; ++ks) {
    pah[ks] = ldfrag(Ph, wid * 16 + r16, ks * 32 + g * 8);
    pal[ks] = ldfrag(Pl, wid * 16 + r16, ks * 32 + g * 8);
  }

  size_t obase = ((size_t)b * 64 + ch) << 16;
#pragma unroll 1
  for (int c8 = 0; c8 < 8; ++c8) {
    const int cd = hd * 8 + c8;
    asm volatile("s_waitcnt vmcnt(0)" ::: "memory");
    __syncthreads();  // raw tau ready
    // eval V, write TRANSPOSED planes [64 d][PST n] (packed b128 writes)
#pragma unroll
    for (int rr = 0; rr < 2; ++rr) {
      int lr = lr0 + rr * 8;
      int nb = (lr & 7) * 8;
      int dcol = ((lr >> 3) << 5) + w0;
      float o[8];
      conv_eval_lds(rawV, wv, lr, w0, cd, o);
      short8 hv, lv;
#pragma unroll
      for (int i = 0; i < 8; ++i) {
        u16 h, l;
        fsplit(o[i], h, l);
        hv[i] = (short)h;
        lv[i] = (short)l;
      }
      *(short8*)&Vh[dcol * PST + nb] = hv;
      *(short8*)&Vl[dcol * PST + nb] = lv;
    }
    __syncthreads();  // planes ready; raw consumed
    if (c8 < 7) issue_raw_v(vpl, rawV, cd + 1, wid, lane);  // async
    f4 po[4];
#pragma unroll
    for (int cb = 0; cb < 4; ++cb)
#pragma unroll
      for (int e = 0; e < 4; ++e) po[cb][e] = 0.f;
#pragma unroll
    for (int ks = 0; ks < 2; ++ks) {
      const int ko = ks * 32 + g * 8;
#pragma unroll
      for (int cb = 0; cb < 4; ++cb) {
        short8 bh = ldfrag(Vh, cb * 16 + r16, ko);
        short8 bl = ldfrag(Vl, cb * 16 + r16, ko);
        po[cb] = __builtin_amdgcn_mfma_f32_16x16x32_bf16(pah[ks], bh, po[cb], 0, 0, 0);
        po[cb] = __builtin_amdgcn_mfma_f32_16x16x32_bf16(pah[ks], bl, po[cb], 0, 0, 0);
        po[cb] = __builtin_amdgcn_mfma_f32_16x16x32_bf16(pal[ks], bh, po[cb], 0, 0, 0);
      }
    }
#pragma unroll
    for (int cb = 0; cb < 4; ++cb)
#pragma unroll
      for (int r = 0; r < 4; ++r) {
        int n = wid * 16 + g * 4 + r;
        int d = cd * 64 + cb * 16 + r16;
        int hh = ((d >> 5) << 3) + (n >> 3);
        int ww = ((d & 31) << 3) + (n & 7);
        out[obase + hh * 256 + ww] = po[cb][r];
      }
  }
}

extern "C" void kernel_launch(void* const* d_in, const int* in_sizes, int n_in,
                              void* d_out, int out_size, void* d_ws,
                              size_t ws_size, hipStream_t stream) {
  const float* x = (const float*)d_in[0];
  const float* wqkv = (const float*)d_in[1];
  const float* wdw = (const float*)d_in[2];
  const float* wproj = (const float*)d_in[3];
  const float* temp = (const float*)d_in[4];
  float* out = (float*)d_out;
  float* qkv0 = (float*)d_ws;  // 402,653,184 bytes (S/sumsq stash inside)

  k_pwm<192><<<2048, 256, 0, stream>>>(x, wqkv, qkv0);
  k_qkt<<<1024, 256, 0, stream>>>(qkv0, wdw);
  k_pv<<<1024, 256, 0, stream>>>(qkv0, wdw, temp, out);
  k_pwm<64><<<2048, 256, 0, stream>>>(out, wproj, out);
}

// Round 15
// 312.229 us; speedup vs baseline: 1.1636x; 1.0043x over previous
//
#include <hip/hip_runtime.h>
#include <hip/hip_bf16.h>

// CxNNxNN attention. B=8, C=64, H=W=256, head=8, N=8.
// token n = (h&7)*8 + (w&7)  [64], feature d = (h>>3)*32 + (w>>3)  [1024].

typedef __attribute__((ext_vector_type(8))) short short8;  // 8 bf16 (4 VGPR)
typedef __attribute__((ext_vector_type(4))) float f4;      // MFMA acc
typedef unsigned short u16;

#define PST 72  // bf16 plane row stride (ushorts)

// Manual barriers (R15): __syncthreads() forces s_waitcnt vmcnt(0) -> drains
// all outstanding global STORES each tile (~30us serialized store drain in
// k_pwm). LDS ordering only needs lgkmcnt; stores drain in background.
__device__ __forceinline__ void bar_lgkm() {
  asm volatile("s_waitcnt lgkmcnt(0)\n\ts_barrier" ::: "memory");
}
__device__ __forceinline__ void bar_vm0_lgkm() {  // DMA ready, no stores out
  asm volatile("s_waitcnt vmcnt(0) lgkmcnt(0)\n\ts_barrier" ::: "memory");
}
__device__ __forceinline__ void bar_vm16_lgkm() {  // allow 16 newest (stores)
  asm volatile("s_waitcnt vmcnt(16) lgkmcnt(0)\n\ts_barrier" ::: "memory");
}

// ---------------- bf16 hi/lo helpers ----------------
__device__ __forceinline__ float tof(u16 u) {
  return __builtin_bit_cast(float, ((unsigned)u) << 16);
}
__device__ __forceinline__ void fsplit(float o, u16& h, u16& l) {
  unsigned u = __builtin_bit_cast(unsigned, o);
  h = (u16)(u >> 16);  // truncate; lo compensates
  float hf = __builtin_bit_cast(float, u & 0xffff0000u);
  l = (u16)(__builtin_bit_cast(unsigned, o - hf) >> 16);
}
__device__ __forceinline__ short8 ldfrag(const u16* p, int row, int ko) {
  return *(const short8*)&p[row * PST + ko];
}

// async global->LDS row DMA: one instr = one 256-float row (64 lanes x 16B)
__device__ __forceinline__ void gload_row(const float* g, float* l) {
  __builtin_amdgcn_global_load_lds(
      (const __attribute__((address_space(1))) unsigned*)g,
      (__attribute__((address_space(3))) unsigned*)l, 16, 0, 0);
}

// ---------------- K1/K3: pointwise GEMM on MFMA (R12 + manual barriers) ------
template <int OC>
__global__ __launch_bounds__(256) void k_pwm(const float* in,
                                             const float* __restrict__ w,
                                             float* outp) {
  constexpr int MT = OC / 64;
  __shared__ u16 XTh[64 * PST], XTl[64 * PST];
  const int t = threadIdx.x;
  const int px = t & 63, cg = t >> 6;
  const int g = (t >> 4) & 3, r16 = t & 15;
  const int oc0 = cg * 16 * MT;
  const size_t pix0 = (size_t)blockIdx.x * 256;  // 4 tiles of 64 px
  const int b = (int)(pix0 >> 16);
  const int hwb = (int)(pix0 & 65535);
  const float* ibase = in + ((size_t)b << 22);

  short8 ah[MT][2], al[MT][2];
#pragma unroll
  for (int m = 0; m < MT; ++m)
#pragma unroll
    for (int ks = 0; ks < 2; ++ks) {
      const float* wr = w + (oc0 + m * 16 + r16) * 64 + ks * 32 + g * 8;
      float4 a0 = *(const float4*)wr;
      float4 a1 = *(const float4*)(wr + 4);
      float av[8] = {a0.x, a0.y, a0.z, a0.w, a1.x, a1.y, a1.z, a1.w};
      short8 h8, l8;
#pragma unroll
      for (int e = 0; e < 8; ++e) {
        u16 h, l;
        fsplit(av[e], h, l);
        h8[e] = (short)h;
        l8[e] = (short)l;
      }
      ah[m][ks] = h8;
      al[m][ks] = l8;
    }

  float xr[16];
#pragma unroll
  for (int j = 0; j < 16; ++j)
    xr[j] = ibase[((size_t)(cg * 16 + j) << 16) + hwb + px];

#pragma unroll 1
  for (int tau = 0; tau < 4; ++tau) {
    const int hw0 = hwb + tau * 64;
#pragma unroll
    for (int jh = 0; jh < 2; ++jh) {
      short8 hv, lv;
#pragma unroll
      for (int e = 0; e < 8; ++e) {
        u16 h, l;
        fsplit(xr[jh * 8 + e], h, l);
        hv[e] = (short)h;
        lv[e] = (short)l;
      }
      *(short8*)&XTh[px * PST + cg * 16 + jh * 8] = hv;
      *(short8*)&XTl[px * PST + cg * 16 + jh * 8] = lv;
    }
    bar_lgkm();  // staging writes visible; stores NOT drained
    if (tau < 3) {
#pragma unroll
      for (int j = 0; j < 16; ++j)
        xr[j] = ibase[((size_t)(cg * 16 + j) << 16) + hw0 + 64 + px];
    }
    float* ob = outp + (((size_t)b * OC) << 16) + hw0;
#pragma unroll
    for (int m = 0; m < MT; ++m)
#pragma unroll
      for (int nt = 0; nt < 4; ++nt) {
        f4 acc;
#pragma unroll
        for (int e = 0; e < 4; ++e) acc[e] = 0.f;
#pragma unroll
        for (int ks = 0; ks < 2; ++ks) {
          short8 bh = ldfrag(XTh, nt * 16 + r16, ks * 32 + g * 8);
          short8 bl = ldfrag(XTl, nt * 16 + r16, ks * 32 + g * 8);
          acc = __builtin_amdgcn_mfma_f32_16x16x32_bf16(ah[m][ks], bh, acc, 0, 0, 0);
          acc = __builtin_amdgcn_mfma_f32_16x16x32_bf16(ah[m][ks], bl, acc, 0, 0, 0);
          acc = __builtin_amdgcn_mfma_f32_16x16x32_bf16(al[m][ks], bh, acc, 0, 0, 0);
        }
#pragma unroll
        for (int e = 0; e < 4; ++e) {
          int oc = oc0 + m * 16 + g * 4 + e;
          ob[((size_t)oc << 16) + nt * 16 + r16] = acc[e];
        }
      }
    bar_lgkm();  // frag reads done before next staging; stores keep flying
  }
}

// ---- conv eval from LDS-staged raw rows (raw row j = image row cd*16-1+j) ----
__device__ __forceinline__ void conv_eval_lds(const float* __restrict__ raw,
                                              const float* __restrict__ w9,
                                              int lr, int w0, int cd,
                                              float o[8]) {
  float wm[9], rv[3][10];
#pragma unroll
  for (int dy = 0; dy < 3; ++dy) {
    int hy = cd * 16 + lr - 1 + dy;
    float mm = (hy >= 0 && hy < 256) ? 1.f : 0.f;
    wm[3 * dy] = w9[3 * dy] * mm;
    wm[3 * dy + 1] = w9[3 * dy + 1] * mm;
    wm[3 * dy + 2] = w9[3 * dy + 2] * mm;
    const float* rp = raw + (lr + dy) * 256;
    float4 l0 = *(const float4*)(rp + w0 * 8);
    float4 l1 = *(const float4*)(rp + w0 * 8 + 4);
    float sL = rp[w0 ? w0 * 8 - 1 : 0];
    float sR = rp[w0 * 8 + 8];  // w0=31: in-LDS garbage, selected away
    rv[dy][0] = w0 ? sL : 0.f;
    rv[dy][1] = l0.x; rv[dy][2] = l0.y; rv[dy][3] = l0.z; rv[dy][4] = l0.w;
    rv[dy][5] = l1.x; rv[dy][6] = l1.y; rv[dy][7] = l1.z; rv[dy][8] = l1.w;
    rv[dy][9] = (w0 < 31) ? sR : 0.f;
  }
#pragma unroll
  for (int i = 0; i < 8; ++i) {
    o[i] = fmaf(wm[0], rv[0][i], fmaf(wm[1], rv[0][i + 1], fmaf(wm[2], rv[0][i + 2],
            fmaf(wm[3], rv[1][i], fmaf(wm[4], rv[1][i + 1], fmaf(wm[5], rv[1][i + 2],
            fmaf(wm[6], rv[2][i], fmaf(wm[7], rv[2][i + 1], wm[8] * rv[2][i + 2]))))))));
  }
}

// issue 18 row-DMAs for Q and K (wave w: Q0-8 / Q9-17 / K0-8 / K9-17)
__device__ __forceinline__ void issue_raw_qk(const float* qpl, const float* kpl,
                                             float* rawQ, float* rawK, int cd,
                                             int wid, int lane) {
  const float* src = (wid & 2) ? kpl : qpl;
  float* dst = (wid & 2) ? rawK : rawQ;
#pragma unroll
  for (int j = 0; j < 9; ++j) {
    int rr = (wid & 1) * 9 + j;
    int hy = cd * 16 - 1 + rr;
    hy = hy < 0 ? 0 : (hy > 255 ? 255 : hy);
    gload_row(src + hy * 256 + lane * 4, dst + rr * 256);
  }
}

// issue 18 row-DMAs for V (wave w: rows w*5..min(+5,18))
__device__ __forceinline__ void issue_raw_v(const float* vpl, float* rawV,
                                            int cd, int wid, int lane) {
#pragma unroll
  for (int j = 0; j < 5; ++j) {
    int rr = wid * 5 + j;
    if (rr < 18) {
      int hy = cd * 16 - 1 + rr;
      hy = hy < 0 ? 0 : (hy > 255 ? 255 : hy);
      gload_row(vpl + hy * 256 + lane * 4, rawV + rr * 256);
    }
  }
}

// ---------------- K2a: QK^T partial over a d-half ----------------
__global__ __launch_bounds__(256) void k_qkt(float* qkv0,
                                             const float* __restrict__ wdw) {
  __shared__ float rawQ[18 * 256];
  __shared__ float rawK[18 * 256];
  __shared__ u16 SAh[64 * PST], SAl[64 * PST];
  __shared__ u16 SBh[64 * PST], SBl[64 * PST];
  __shared__ float red[64 * 8];
  const int t = threadIdx.x;
  const int u = blockIdx.x >> 1, hd = blockIdx.x & 1;
  const int b = u >> 6, ch = u & 63;
  float* qpl = qkv0 + (((size_t)b * 192 + ch) << 16);
  const float* kpl = qkv0 + (((size_t)b * 192 + 64 + ch) << 16);
  const int wid = t >> 6, lane = t & 63;
  const int g = (t >> 4) & 3, r16 = t & 15;
  const int lr0 = t >> 5, w0 = t & 31;

  issue_raw_qk(qpl, kpl, rawQ, rawK, hd * 8, wid, lane);  // chunk 0, async

  float wq[9], wk[9];
#pragma unroll
  for (int i = 0; i < 9; ++i) {  // overlap with DMA
    wq[i] = wdw[ch * 9 + i];
    wk[i] = wdw[(64 + ch) * 9 + i];
  }
  f4 acc[4];
#pragma unroll
  for (int cb = 0; cb < 4; ++cb)
#pragma unroll
    for (int e = 0; e < 4; ++e) acc[cb][e] = 0.f;
  float sqQ = 0.f, sqK = 0.f;

#pragma unroll 1
  for (int c8 = 0; c8 < 8; ++c8) {
    const int cd = hd * 8 + c8;
    bar_vm0_lgkm();  // raw tau ready (all waves); no in-loop stores
    // eval Q and K runs (lr0, w0) and (lr0+8, w0); write bf16 hi/lo planes
#pragma unroll
    for (int rr = 0; rr < 2; ++rr) {
      int lr = lr0 + rr * 8;
      int nb = (lr & 7) * 8;
      int dcol = ((lr >> 3) << 5) + w0;
      float oq[8], ok[8];
      conv_eval_lds(rawQ, wq, lr, w0, cd, oq);
      conv_eval_lds(rawK, wk, lr, w0, cd, ok);
#pragma unroll
      for (int i = 0; i < 8; ++i) {
        u16 h, l;
        fsplit(oq[i], h, l);
        SAh[(nb + i) * PST + dcol] = h;
        SAl[(nb + i) * PST + dcol] = l;
        fsplit(ok[i], h, l);
        SBh[(nb + i) * PST + dcol] = h;
        SBl[(nb + i) * PST + dcol] = l;
      }
    }
    bar_lgkm();  // planes ready; raw consumed
    if (c8 < 7)  // async DMA for tau+1 flies under sumsq+MFMA
      issue_raw_qk(qpl, kpl, rawQ, rawK, cd + 1, wid, lane);
    {  // sumsq partials (hi+lo reconstructed): row n=t>>2, 16 cols
      const int n = t >> 2, c0 = (t & 3) << 4;
#pragma unroll
      for (int h2 = 0; h2 < 2; ++h2) {
        short8 qh = *(const short8*)&SAh[n * PST + c0 + 8 * h2];
        short8 ql = *(const short8*)&SAl[n * PST + c0 + 8 * h2];
        short8 kh = *(const short8*)&SBh[n * PST + c0 + 8 * h2];
        short8 kl = *(const short8*)&SBl[n * PST + c0 + 8 * h2];
#pragma unroll
        for (int e = 0; e < 8; ++e) {
          float qv = tof((u16)qh[e]) + tof((u16)ql[e]);
          float kv = tof((u16)kh[e]) + tof((u16)kl[e]);
          sqQ = fmaf(qv, qv, sqQ);
          sqK = fmaf(kv, kv, sqK);
        }
      }
    }
#pragma unroll
    for (int ks = 0; ks < 2; ++ks) {
      const int ko = ks * 32 + g * 8;
      short8 ah = ldfrag(SAh, wid * 16 + r16, ko);
      short8 al = ldfrag(SAl, wid * 16 + r16, ko);
#pragma unroll
      for (int cb = 0; cb < 4; ++cb) {
        short8 bh = ldfrag(SBh, cb * 16 + r16, ko);
        short8 bl = ldfrag(SBl, cb * 16 + r16, ko);
        acc[cb] = __builtin_amdgcn_mfma_f32_16x16x32_bf16(ah, bh, acc[cb], 0, 0, 0);
        acc[cb] = __builtin_amdgcn_mfma_f32_16x16x32_bf16(ah, bl, acc[cb], 0, 0, 0);
        acc[cb] = __builtin_amdgcn_mfma_f32_16x16x32_bf16(al, bh, acc[cb], 0, 0, 0);
      }
    }
  }

  __syncthreads();
  red[(t >> 2) * 8 + (t & 3)] = sqQ;
  red[(t >> 2) * 8 + 4 + (t & 3)] = sqK;
  __syncthreads();
  float* stash = qpl + hd * 32768 + 256;  // S[4096] then sumsq[128]
  if (t < 128) {
    int n = t & 63;
    int o = (t >> 6) * 4;
    float s = red[n * 8 + o] + red[n * 8 + o + 1] + red[n * 8 + o + 2] +
              red[n * 8 + o + 3];
    stash[4096 + (t >> 6) * 64 + n] = s;  // 0..63 = Q, 64..127 = K
  }
#pragma unroll
  for (int cb = 0; cb < 4; ++cb)
#pragma unroll
    for (int r = 0; r < 4; ++r) {
      int n = wid * 16 + g * 4 + r, m = cb * 16 + r16;
      stash[n * 64 + m] = acc[cb][r];
    }
}

// ---------------- K2b: softmax + PV over a d-half ----------------
__global__ __launch_bounds__(256) void k_pv(const float* qkv0,
                                            const float* __restrict__ wdw,
                                            const float* __restrict__ temperature,
                                            float* __restrict__ out) {
  __shared__ float rawV[18 * 256];
  __shared__ u16 Ph[64 * PST], Pl[64 * PST];
  __shared__ u16 Vh[64 * PST], Vl[64 * PST];
  __shared__ float invk[64];
  const int t = threadIdx.x;
  const int u = blockIdx.x >> 1, hd = blockIdx.x & 1;
  const int b = u >> 6, ch = u & 63;
  const float* vpl = qkv0 + (((size_t)b * 192 + 128 + ch) << 16);
  const float* sb0 = qkv0 + (((size_t)b * 192 + ch) << 16) + 256;
  const float* sb1 = sb0 + 32768;
  const int wid = t >> 6, lane = t & 63;
  const int g = (t >> 4) & 3, r16 = t & 15;
  const int lr0 = t >> 5, w0 = t & 31;

  issue_raw_v(vpl, rawV, hd * 8, wid, lane);  // chunk 0, flies under softmax

  float wv[9];
#pragma unroll
  for (int i = 0; i < 9; ++i) wv[i] = wdw[(128 + ch) * 9 + i];
  const float tscale = temperature[ch >> 3];

  if (t < 64) {
    float s = sb0[4096 + 64 + t] + sb1[4096 + 64 + t];
    invk[t] = 1.f / fmaxf(sqrtf(s), 1e-12f);
  }
  bar_lgkm();  // invk visible; does NOT drain chunk-0 DMA

  const int row = wid * 16 + r16;
  float sq = sb0[4096 + row] + sb1[4096 + row];
  const float invq = 1.f / fmaxf(sqrtf(sq), 1e-12f);
  float sv[16];
  const float* s0r = sb0 + row * 64 + g * 16;
  const float* s1r = sb1 + row * 64 + g * 16;
  float mx = -1e30f;
#pragma unroll
  for (int j = 0; j < 16; ++j) {
    sv[j] = (s0r[j] + s1r[j]) * invq * invk[g * 16 + j] * tscale;
    mx = fmaxf(mx, sv[j]);
  }
  mx = fmaxf(mx, __shfl_xor(mx, 16));
  mx = fmaxf(mx, __shfl_xor(mx, 32));
  float ss = 0.f;
#pragma unroll
  for (int j = 0; j < 16; ++j) {
    sv[j] = __expf(sv[j] - mx);
    ss += sv[j];
  }
  ss += __shfl_xor(ss, 16);
  ss += __shfl_xor(ss, 32);
  const float rs = 1.f / ss;
  short8 h0, h1, l0, l1;
#pragma unroll
  for (int j = 0; j < 8; ++j) {
    u16 h, l;
    fsplit(sv[j] * rs, h, l);
    h0[j] = (short)h; l0[j] = (short)l;
    fsplit(sv[8 + j] * rs, h, l);
    h1[j] = (short)h; l1[j] = (short)l;
  }
  *(short8*)&Ph[row * PST + g * 16] = h0;
  *(short8*)&Ph[row * PST + g * 16 + 8] = h1;
  *(short8*)&Pl[row * PST + g * 16] = l0;
  *(short8*)&Pl[row * PST + g * 16 + 8] = l1;
  bar_lgkm();  // P planes visible

  short8 pah[2], pal[2];
#pragma unroll
  for (int ks = 0; ks < 2; ++ks) {
    pah[ks] = ldfrag(Ph, wid * 16 + r16, ks * 32 + g * 8);
    pal[ks] = ldfrag(Pl, wid * 16 + r16, ks * 32 + g * 8);
  }

  size_t obase = ((size_t)b * 64 + ch) << 16;
#pragma unroll 1
  for (int c8 = 0; c8 < 8; ++c8) {
    const int cd = hd * 8 + c8;
    // raw tau ready: DMA rows are older than the 16 newest (prev stores)
    bar_vm16_lgkm();
    // eval V, write TRANSPOSED planes [64 d][PST n] (packed b128 writes)
#pragma unroll
    for (int rr = 0; rr < 2; ++rr) {
      int lr = lr0 + rr * 8;
      int nb = (lr & 7) * 8;
      int dcol = ((lr >> 3) << 5) + w0;
      float o[8];
      conv_eval_lds(rawV, wv, lr, w0, cd, o);
      short8 hv, lv;
#pragma unroll
      for (int i = 0; i < 8; ++i) {
        u16 h, l;
        fsplit(o[i], h, l);
        hv[i] = (short)h;
        lv[i] = (short)l;
      }
      *(short8*)&Vh[dcol * PST + nb] = hv;
      *(short8*)&Vl[dcol * PST + nb] = lv;
    }
    bar_lgkm();  // planes ready; raw consumed; prev stores NOT drained
    if (c8 < 7) issue_raw_v(vpl, rawV, cd + 1, wid, lane);  // async
    f4 po[4];
#pragma unroll
    for (int cb = 0; cb < 4; ++cb)
#pragma unroll
      for (int e = 0; e < 4; ++e) po[cb][e] = 0.f;
#pragma unroll
    for (int ks = 0; ks < 2; ++ks) {
      const int ko = ks * 32 + g * 8;
#pragma unroll
      for (int cb = 0; cb < 4; ++cb) {
        short8 bh = ldfrag(Vh, cb * 16 + r16, ko);
        short8 bl = ldfrag(Vl, cb * 16 + r16, ko);
        po[cb] = __builtin_amdgcn_mfma_f32_16x16x32_bf16(pah[ks], bh, po[cb], 0, 0, 0);
        po[cb] = __builtin_amdgcn_mfma_f32_16x16x32_bf16(pah[ks], bl, po[cb], 0, 0, 0);
        po[cb] = __builtin_amdgcn_mfma_f32_16x16x32_bf16(pal[ks], bh, po[cb], 0, 0, 0);
      }
    }
#pragma unroll
    for (int cb = 0; cb < 4; ++cb)
#pragma unroll
      for (int r = 0; r < 4; ++r) {
        int n = wid * 16 + g * 4 + r;
        int d = cd * 64 + cb * 16 + r16;
        int hh = ((d >> 5) << 3) + (n >> 3);
        int ww = ((d & 31) << 3) + (n & 7);
        out[obase + hh * 256 + ww] = po[cb][r];
      }
  }
}

extern "C" void kernel_launch(void* const* d_in, const int* in_sizes, int n_in,
                              void* d_out, int out_size, void* d_ws,
                              size_t ws_size, hipStream_t stream) {
  const float* x = (const float*)d_in[0];
  const float* wqkv = (const float*)d_in[1];
  const float* wdw = (const float*)d_in[2];
  const float* wproj = (const float*)d_in[3];
  const float* temp = (const float*)d_in[4];
  float* out = (float*)d_out;
  float* qkv0 = (float*)d_ws;  // 402,653,184 bytes (S/sumsq stash inside)

  k_pwm<192><<<2048, 256, 0, stream>>>(x, wqkv, qkv0);
  k_qkt<<<1024, 256, 0, stream>>>(qkv0, wdw);
  k_pv<<<1024, 256, 0, stream>>>(qkv0, wdw, temp, out);
  k_pwm<64><<<2048, 256, 0, stream>>>(out, wproj, out);
}